// Round 17
// baseline (619.493 us; speedup 1.0000x reference)
//
#include <hip/hip_runtime.h>
#include <math.h>

// ---------------------------------------------------------------------------
// Problem constants: B=8, C=512, H=W=64, N=4096, groups=4 (128 ch/group),
// heads=4 (hd=128), k_max=256 rope pairs, rope angle = wpos * theta[kidx].
// ---------------------------------------------------------------------------

typedef __attribute__((ext_vector_type(8))) short bf8;     // 8 bf16 (4 VGPR)
typedef __attribute__((ext_vector_type(4))) float f32x4;   // MFMA acc

__device__ __forceinline__ float waveSum(float v) {
  #pragma unroll
  for (int o = 32; o; o >>= 1) v += __shfl_down(v, o, 64);
  return v;
}

__device__ __forceinline__ unsigned short f2bf(float f) {
  unsigned u = __float_as_uint(f);
  unsigned r = u + 0x7fffu + ((u >> 16) & 1u);
  return (unsigned short)(r >> 16);
}

__device__ __forceinline__ float bf2f(unsigned short u) {
  return __uint_as_float((unsigned)u << 16);
}

__device__ __forceinline__ void gload_lds16(const void* g, void* l) {
  __builtin_amdgcn_global_load_lds(
      (const __attribute__((address_space(1))) unsigned*)g,
      (__attribute__((address_space(3))) unsigned*)l, 16, 0, 0);
}

// ---------------- rope cos/sin table: tab[wpos*256 + kidx] = {cos,sin} ------
__global__ __launch_bounds__(256) void k_ropetab(float* __restrict__ tab) {
  int idx = blockIdx.x * 256 + threadIdx.x;   // 16384 = 64 wpos * 256 kidx
  int w = idx >> 8, kk = idx & 255;
  float theta = powf(10000.0f, -(float)kk * (1.0f / 256.0f));
  float ang = (float)w * theta;
  tab[2 * idx]     = cosf(ang);
  tab[2 * idx + 1] = sinf(ang);
}

// ---------------- depthwise conv: 16 px/thread, 256 thr (rounds 5-7 proven) -
// sm [72][73]; map r=tid>>2, cb=(tid&3)*16: bank = (9r' + 16q) mod 32 over a
// wave -> all 32 banks x 2 lanes (free, m136). Per-level acc[16] only --
// cross-level merging spills (rounds 6/9/11/15). 16px halves LDS-read
// instructions per pixel vs 8px (524/thread x1 wave vs 332 x2 waves).
template <int K>
__device__ __forceinline__ void conv16px(float (*sm)[73], const float* wl,
                                         int r, int cb, float bias, float acc[16]) {
  constexpr int P = (K - 1) / 2;
  #pragma unroll
  for (int i = 0; i < 16; i++) acc[i] = bias;
  #pragma unroll
  for (int dy = 0; dy < K; ++dy) {
    const float* row = &sm[r + dy - P + 4][cb - P + 4];
    float v[16 + K - 1];
    #pragma unroll
    for (int o = 0; o < 16 + K - 1; ++o) v[o] = row[o];
    #pragma unroll
    for (int dx = 0; dx < K; ++dx) {
      float wv = wl[dy * K + dx];
      #pragma unroll
      for (int i = 0; i < 16; i++) acc[i] = fmaf(wv, v[i + dx], acc[i]);
    }
  }
}

__device__ __forceinline__ void load_plane256(const float* __restrict__ xp,
                                              float (*sm)[73], int tid) {
  for (int idx = tid; idx < 5184; idx += 256) {
    int pr = idx / 72, pc = idx - pr * 72;
    int gr = pr - 4, gc = pc - 4;
    float v = 0.f;
    if ((unsigned)gr < 64u && (unsigned)gc < 64u) v = xp[gr * 64 + gc];
    sm[pr][pc] = v;
  }
}

__device__ __forceinline__ void load_weights256(const float* w0, const float* w1,
                                                const float* w2, const float* w3,
                                                float* wl, int c, int tid) {
  if (tid < 9)               wl[tid] = w0[c * 9  + tid];
  else if (tid < 34)         wl[tid] = w1[c * 25 + tid - 9];
  else if (tid < 83)         wl[tid] = w2[c * 49 + tid - 34];
  else if (tid < 164)        wl[tid] = w3[c * 81 + tid - 83];
}

__device__ __forceinline__ void reduce_write2_256(float s, float sq, float* red,
                                                  int tid, float* dst) {
  s = waveSum(s); sq = waveSum(sq);
  int wid = tid >> 6, lane = tid & 63;
  if (lane == 0) { red[wid] = s; red[4 + wid] = sq; }
  __syncthreads();
  if (tid == 0) {
    dst[0] = red[0] + red[1] + red[2] + red[3];
    dst[1] = red[4] + red[5] + red[6] + red[7];
  }
  __syncthreads();
}

// ---------------- single-staging conv: 16px/thread, per-level accs ----------
__global__ __launch_bounds__(256) void k_conv4(
    const float* __restrict__ x,
    const float* __restrict__ w0, const float* __restrict__ b0,
    const float* __restrict__ w1, const float* __restrict__ b1,
    const float* __restrict__ w2, const float* __restrict__ b2,
    const float* __restrict__ w3, const float* __restrict__ b3,
    float* __restrict__ part,
    unsigned short* __restrict__ l0, unsigned short* __restrict__ l1,
    unsigned short* __restrict__ l2, unsigned short* __restrict__ l3) {
  __shared__ float sm[72][73];
  __shared__ float wl[164];
  __shared__ float red[8];
  int tid = threadIdx.x;
  int bc = blockIdx.x;             // b*512 + c
  int b = bc >> 9, c = bc & 511;
  load_plane256(x + (size_t)bc * 4096, sm, tid);
  load_weights256(w0, w1, w2, w3, wl, c, tid);
  __syncthreads();
  int r = tid >> 2, cb = (tid & 3) << 4;
  size_t obase = (size_t)bc * 4096 + r * 64 + cb;
  float acc[16];
  float s, sq;
  unsigned short o[16];

  // ---- level 0 (K=3) ----
  conv16px<3>(sm, &wl[0], r, cb, b0[c], acc);
  s = 0; sq = 0;
  #pragma unroll
  for (int i = 0; i < 16; i++) {
    s += acc[i]; sq = fmaf(acc[i], acc[i], sq); o[i] = f2bf(acc[i]);
  }
  *(uint4*)&l0[obase]     = *(uint4*)&o[0];
  *(uint4*)&l0[obase + 8] = *(uint4*)&o[8];
  reduce_write2_256(s, sq, red, tid, part + ((size_t)(0 * 8 + b) * 512 + c) * 2);
  __builtin_amdgcn_sched_barrier(0);

  // ---- level 1 (K=5) ----
  conv16px<5>(sm, &wl[9], r, cb, b1[c], acc);
  s = 0; sq = 0;
  #pragma unroll
  for (int i = 0; i < 16; i++) {
    s += acc[i]; sq = fmaf(acc[i], acc[i], sq); o[i] = f2bf(acc[i]);
  }
  *(uint4*)&l1[obase]     = *(uint4*)&o[0];
  *(uint4*)&l1[obase + 8] = *(uint4*)&o[8];
  reduce_write2_256(s, sq, red, tid, part + ((size_t)(1 * 8 + b) * 512 + c) * 2);
  __builtin_amdgcn_sched_barrier(0);

  // ---- level 2 (K=7) ----
  conv16px<7>(sm, &wl[34], r, cb, b2[c], acc);
  s = 0; sq = 0;
  #pragma unroll
  for (int i = 0; i < 16; i++) {
    s += acc[i]; sq = fmaf(acc[i], acc[i], sq); o[i] = f2bf(acc[i]);
  }
  *(uint4*)&l2[obase]     = *(uint4*)&o[0];
  *(uint4*)&l2[obase + 8] = *(uint4*)&o[8];
  reduce_write2_256(s, sq, red, tid, part + ((size_t)(2 * 8 + b) * 512 + c) * 2);
  __builtin_amdgcn_sched_barrier(0);

  // ---- level 3 (K=9) ----
  conv16px<9>(sm, &wl[83], r, cb, b3[c], acc);
  s = 0; sq = 0;
  #pragma unroll
  for (int i = 0; i < 16; i++) {
    s += acc[i]; sq = fmaf(acc[i], acc[i], sq); o[i] = f2bf(acc[i]);
  }
  *(uint4*)&l3[obase]     = *(uint4*)&o[0];
  *(uint4*)&l3[obase + 8] = *(uint4*)&o[8];
  reduce_write2_256(s, sq, red, tid, part + ((size_t)(3 * 8 + b) * 512 + c) * 2);
}

// ---------------- GN stats: mean/rstd per (level,b,group) -------------------
__global__ __launch_bounds__(128) void k_gn_stats(const float* __restrict__ part,
                                                  float* __restrict__ stats) {
  int blk = blockIdx.x;            // l*32 + b*4 + g, 128 blocks
  int tid = threadIdx.x;           // 128 = channels within group
  int g = blk & 3, bb = (blk >> 2) & 7, l = blk >> 5;
  const float* p = part + ((size_t)(l * 8 + bb) * 512 + g * 128 + tid) * 2;
  float s = p[0], sq = p[1];
  s = waveSum(s); sq = waveSum(sq);
  __shared__ float red[4];
  int wid = tid >> 6, lane = tid & 63;
  if (lane == 0) { red[wid] = s; red[2 + wid] = sq; }
  __syncthreads();
  if (tid == 0) {
    float S = red[0] + red[1], SQ = red[2] + red[3];
    const float inv = 1.0f / (128.0f * 4096.0f);
    float mean = S * inv;
    float var = SQ * inv - mean * mean;
    stats[blk * 2] = mean;
    stats[blk * 2 + 1] = rsqrtf(var + 1e-5f);
  }
}

// ---------------- fused GN+sigmoid+avg: write bf16 NCHW + bf16 token-major --
__global__ __launch_bounds__(256) void k_fused_tp(
    const unsigned short* __restrict__ l0, const unsigned short* __restrict__ l1,
    const unsigned short* __restrict__ l2, const unsigned short* __restrict__ l3,
    const float* __restrict__ gw0, const float* __restrict__ gb0,
    const float* __restrict__ gw1, const float* __restrict__ gb1,
    const float* __restrict__ gw2, const float* __restrict__ gb2,
    const float* __restrict__ gw3, const float* __restrict__ gb3,
    const float* __restrict__ stats, unsigned short* __restrict__ fnchw,
    unsigned short* __restrict__ fbf) {
  __shared__ float smT[64][65];
  int tid = threadIdx.x;
  int bid = blockIdx.x;            // b(8) x ct(8) x nt(64)
  int nt = bid & 63, ct = (bid >> 6) & 7, b = bid >> 9;
  int c0 = ct << 6, n0 = nt << 6;
  int c_loc = tid >> 2, nq = tid & 3;
  int c = c0 + c_loc, g = c >> 7;
  float m0 = stats[(0 * 32 + b * 4 + g) * 2], r0 = stats[(0 * 32 + b * 4 + g) * 2 + 1];
  float m1 = stats[(1 * 32 + b * 4 + g) * 2], r1 = stats[(1 * 32 + b * 4 + g) * 2 + 1];
  float m2 = stats[(2 * 32 + b * 4 + g) * 2], r2 = stats[(2 * 32 + b * 4 + g) * 2 + 1];
  float m3 = stats[(3 * 32 + b * 4 + g) * 2], r3 = stats[(3 * 32 + b * 4 + g) * 2 + 1];
  float a0 = r0 * gw0[c], c0p = gb0[c] - m0 * a0;
  float a1 = r1 * gw1[c], c1p = gb1[c] - m1 * a1;
  float a2 = r2 * gw2[c], c2p = gb2[c] - m2 * a2;
  float a3 = r3 * gw3[c], c3p = gb3[c] - m3 * a3;
  size_t base = ((size_t)b * 512 + c) * 4096 + n0 + nq * 16;
  uint4 u0a = *(const uint4*)&l0[base], u0b = *(const uint4*)&l0[base + 8];
  uint4 u1a = *(const uint4*)&l1[base], u1b = *(const uint4*)&l1[base + 8];
  uint4 u2a = *(const uint4*)&l2[base], u2b = *(const uint4*)&l2[base + 8];
  uint4 u3a = *(const uint4*)&l3[base], u3b = *(const uint4*)&l3[base + 8];
  float outv[16];
  #pragma unroll
  for (int i = 0; i < 8; i++) {
    float t0 = fmaf(bf2f(((const unsigned short*)&u0a)[i]), a0, c0p);
    float t1 = fmaf(bf2f(((const unsigned short*)&u1a)[i]), a1, c1p);
    float t2 = fmaf(bf2f(((const unsigned short*)&u2a)[i]), a2, c2p);
    float t3 = fmaf(bf2f(((const unsigned short*)&u3a)[i]), a3, c3p);
    float s = 1.0f / (1.0f + __expf(-t0)) + 1.0f / (1.0f + __expf(-t1)) +
              1.0f / (1.0f + __expf(-t2)) + 1.0f / (1.0f + __expf(-t3));
    outv[i] = s * 0.25f;
  }
  #pragma unroll
  for (int i = 0; i < 8; i++) {
    float t0 = fmaf(bf2f(((const unsigned short*)&u0b)[i]), a0, c0p);
    float t1 = fmaf(bf2f(((const unsigned short*)&u1b)[i]), a1, c1p);
    float t2 = fmaf(bf2f(((const unsigned short*)&u2b)[i]), a2, c2p);
    float t3 = fmaf(bf2f(((const unsigned short*)&u3b)[i]), a3, c3p);
    float s = 1.0f / (1.0f + __expf(-t0)) + 1.0f / (1.0f + __expf(-t1)) +
              1.0f / (1.0f + __expf(-t2)) + 1.0f / (1.0f + __expf(-t3));
    outv[8 + i] = s * 0.25f;
  }
  unsigned short ob[16];
  #pragma unroll
  for (int i = 0; i < 16; i++) ob[i] = f2bf(outv[i]);
  *(uint4*)&fnchw[base]     = *(uint4*)&ob[0];
  *(uint4*)&fnchw[base + 8] = *(uint4*)&ob[8];
  #pragma unroll
  for (int i = 0; i < 16; i++) smT[c_loc][nq * 16 + i] = outv[i];
  __syncthreads();
  int cc = tid & 63, r_s = tid >> 6;
  #pragma unroll
  for (int rr = 0; rr < 64; rr += 4)
    fbf[((size_t)b * 4096 + n0 + rr + r_s) * 512 + c0 + cc] = f2bf(smT[cc][rr + r_s]);
}

// ---------------- weight convert: qkw f32 [1024][512] -> bf16 ---------------
__global__ __launch_bounds__(256) void k_wcvt(const float* __restrict__ qkw,
                                              unsigned short* __restrict__ wbf) {
  int gid = blockIdx.x * 256 + threadIdx.x;   // 131072 threads x4 elems
  float4 v = *(const float4*)&qkw[(size_t)gid * 4];
  short4 o;
  o.x = (short)f2bf(v.x); o.y = (short)f2bf(v.y);
  o.z = (short)f2bf(v.z); o.w = (short)f2bf(v.w);
  *(short4*)&wbf[(size_t)gid * 4] = o;
}

// ---------------- qk GEMM (bf16 MFMA): bf16 q/k outputs ---------------------
__global__ __launch_bounds__(256) void k_qk(const unsigned short* __restrict__ fbf,
                                            const unsigned short* __restrict__ wbf,
                                            unsigned short* __restrict__ qbf,
                                            unsigned short* __restrict__ kbf) {
  __shared__ __align__(16) short As[8192];   // 128 rows x 64 bf16 (swizzled)
  __shared__ __align__(16) short Bs[8192];
  int tid = threadIdx.x;
  int bid = blockIdx.x;
  // bijective XCD swizzle (2048 % 8 == 0): XCD x works batch x entirely.
  int sw = (bid & 7) * 256 + (bid >> 3);
  int b = sw >> 8, rem = sw & 255;
  int mt_blk = rem >> 3, jt = rem & 7;
  int m0 = mt_blk << 7, j0 = jt << 7;
  int lane = tid & 63, wid = tid >> 6;
  int wm = (wid >> 1) * 64, wn = (wid & 1) * 64;
  int l15 = lane & 15, l4 = lane >> 4;

  const unsigned short* Ab = fbf + (size_t)b * 4096 * 512;
  f32x4 acc[4][4];
  #pragma unroll
  for (int i = 0; i < 4; i++)
    #pragma unroll
    for (int j = 0; j < 4; j++) acc[i][j] = (f32x4)0.f;

  int srow[4], sperm[4];
  #pragma unroll
  for (int i = 0; i < 4; i++) {
    int s = i * 256 + tid;
    srow[i] = s >> 3;
    sperm[i] = (s & 7) ^ (srow[i] & 7);
  }

  for (int t = 0; t < 8; ++t) {
    int c0 = t << 6;
    if (t) __syncthreads();
    #pragma unroll
    for (int i = 0; i < 4; i++) {
      int s = i * 256 + tid;
      gload_lds16(Ab + (size_t)(m0 + srow[i]) * 512 + c0 + sperm[i] * 8,
                  (char*)As + s * 16);
      gload_lds16(wbf + (size_t)(j0 + srow[i]) * 512 + c0 + sperm[i] * 8,
                  (char*)Bs + s * 16);
    }
    __syncthreads();
    #pragma unroll
    for (int ks = 0; ks < 2; ++ks) {
      bf8 af[4], bfr[4];
      #pragma unroll
      for (int mt = 0; mt < 4; mt++) {
        int row = wm + mt * 16 + l15;
        int g = ks * 4 + l4;
        af[mt] = *(const bf8*)((const char*)As + row * 128 + ((g ^ (row & 7)) << 4));
      }
      #pragma unroll
      for (int nt = 0; nt < 4; nt++) {
        int row = wn + nt * 16 + l15;
        int g = ks * 4 + l4;
        bfr[nt] = *(const bf8*)((const char*)Bs + row * 128 + ((g ^ (row & 7)) << 4));
      }
      #pragma unroll
      for (int mt = 0; mt < 4; mt++)
        #pragma unroll
        for (int nt = 0; nt < 4; nt++)
          acc[mt][nt] = __builtin_amdgcn_mfma_f32_16x16x32_bf16(
              af[mt], bfr[nt], acc[mt][nt], 0, 0, 0);
    }
  }

  unsigned short* dst; int jb;
  if (j0 < 512) { dst = qbf; jb = j0; } else { dst = kbf; jb = j0 - 512; }
  #pragma unroll
  for (int mt = 0; mt < 4; mt++) {
    #pragma unroll
    for (int nt = 0; nt < 4; nt++) {
      #pragma unroll
      for (int r = 0; r < 4; r++) {
        float v = acc[mt][nt][r];
        v = v > 0.f ? v + 1.f : __expf(v);   // elu(x)+1
        int token = m0 + wm + mt * 16 + l4 * 4 + r;
        int chan = jb + wn + nt * 16 + l15;
        dst[((size_t)b * 4096 + token) * 512 + chan] = f2bf(v);
      }
    }
  }
}

// ---------------- krT: transpose+rope kbf bf16 [n][c] -> krT bf16 [c][n] ----
__global__ __launch_bounds__(256) void k_krT(const unsigned short* __restrict__ kbf,
                                             const float* __restrict__ tab,
                                             unsigned short* __restrict__ krT,
                                             float* __restrict__ kmp) {
  __shared__ float sm[64][65];
  int tid = threadIdx.x;
  int bid = blockIdx.x;            // b(8) x ct(8) x nt(64)
  int nt = bid & 63, ct = (bid >> 6) & 7, b = bid >> 9;
  int c0 = ct << 6, n0 = nt << 6;
  int cc = tid & 63, n_s = tid >> 6;
  #pragma unroll
  for (int nn = 0; nn < 64; nn += 4)
    sm[cc][nn + n_s] =
        bf2f(kbf[((size_t)b * 4096 + n0 + nn + n_s) * 512 + c0 + cc]);
  __syncthreads();
  int rc = tid >> 2, nq = tid & 3;
  int c = c0 + rc;
  int pairidx = c >> 1;
  int odd = c & 1;
  int partner = odd ? rc - 1 : rc + 1;
  unsigned short o[16];
  float colsum = 0.f;
  #pragma unroll
  for (int i = 0; i < 16; i++) {
    int nloc = nq * 16 + i;                    // wpos = nloc (n0 % 64 == 0)
    float2 cs = *(const float2*)&tab[2 * (nloc * 256 + pairidx)];
    float a = sm[rc][nloc], p = sm[partner][nloc];
    float r = odd ? fmaf(cs.x, a, cs.y * p) : fmaf(cs.x, a, -cs.y * p);
    o[i] = f2bf(r);
    colsum += a;                               // un-roped for kmean
  }
  *(uint4*)&krT[((size_t)b * 512 + c) * 4096 + n0 + nq * 16]     = *(uint4*)&o[0];
  *(uint4*)&krT[((size_t)b * 512 + c) * 4096 + n0 + nq * 16 + 8] = *(uint4*)&o[8];
  colsum += __shfl_xor(colsum, 1, 64);
  colsum += __shfl_xor(colsum, 2, 64);
  if (nq == 0) kmp[((size_t)b * 64 + nt) * 512 + c] = colsum;
}

// ---------------- kmean finalize ---------------------------------------------
__global__ __launch_bounds__(512) void k_kmean_fin(const float* __restrict__ kmp,
                                                   float* __restrict__ kmean) {
  int b = blockIdx.x, c = threadIdx.x;
  float s = 0.f;
  for (int nt = 0; nt < 64; nt++) s += kmp[((size_t)b * 64 + nt) * 512 + c];
  kmean[b * 512 + c] = s * (1.0f / 4096.0f);
}

// ---------------- z + q_rope fused, COALESCED, bf16 q input -----------------
__global__ __launch_bounds__(256) void k_zrope(const unsigned short* __restrict__ qbf,
                                               const float* __restrict__ kmean,
                                               const float* __restrict__ tab,
                                               float* __restrict__ zbuf,
                                               unsigned short* __restrict__ qr) {
  __shared__ float kml[512];
  int tid = threadIdx.x;
  int blk = blockIdx.x;            // 8192 blocks x 4 tokens
  int b = blk >> 10;               // 1024 blocks per batch
  kml[tid] = kmean[b * 512 + tid];
  kml[tid + 256] = kmean[b * 512 + 256 + tid];
  __syncthreads();
  int tok = blk * 4 + (tid >> 6);  // global token index (b*4096 + n)
  int pg = tid & 63;
  int n = tok & 4095;
  int wpos = n & 63;
  uint4 qu = *(const uint4*)&qbf[(size_t)tok * 512 + pg * 8];
  const unsigned short* qs = (const unsigned short*)&qu;
  float4 a  = make_float4(bf2f(qs[0]), bf2f(qs[1]), bf2f(qs[2]), bf2f(qs[3]));
  float4 b4 = make_float4(bf2f(qs[4]), bf2f(qs[5]), bf2f(qs[6]), bf2f(qs[7]));
  const float* tp = tab + 2 * (wpos * 256 + pg * 4);
  float4 t0 = *(const float4*)&tp[0];   // pairs 4pg, 4pg+1
  float4 t1 = *(const float4*)&tp[4];   // pairs 4pg+2, 4pg+3
  unsigned short o[8];
  o[0] = f2bf(t0.x * a.x - t0.y * a.y);
  o[1] = f2bf(t0.x * a.y + t0.y * a.x);
  o[2] = f2bf(t0.z * a.z - t0.w * a.w);
  o[3] = f2bf(t0.z * a.w + t0.w * a.z);
  o[4] = f2bf(t1.x * b4.x - t1.y * b4.y);
  o[5] = f2bf(t1.x * b4.y + t1.y * b4.x);
  o[6] = f2bf(t1.z * b4.z - t1.w * b4.w);
  o[7] = f2bf(t1.z * b4.w + t1.w * b4.z);
  *(uint4*)&qr[(size_t)tok * 512 + pg * 8] = *(uint4*)o;
  // z partial: dot(q[pg*8..+7], kmean[pg*8..+7])
  const float* km = &kml[pg * 8];
  float4 ka = *(const float4*)&km[0];
  float4 kb = *(const float4*)&km[4];
  float dot = a.x * ka.x + a.y * ka.y + a.z * ka.z + a.w * ka.w +
              b4.x * kb.x + b4.y * kb.y + b4.z * kb.z + b4.w * kb.w;
  dot += __shfl_xor(dot, 1, 64);
  dot += __shfl_xor(dot, 2, 64);
  dot += __shfl_xor(dot, 4, 64);
  dot += __shfl_xor(dot, 8, 64);
  if ((pg & 15) == 0) {
    int h = pg >> 4;
    zbuf[(size_t)(b * 4 + h) * 4096 + n] = 1.0f / (dot + 1e-6f);
  }
}

// ---------------- kv GEMM: both operands via gload_lds16 (bf16 NCHW V) ------
__global__ __launch_bounds__(256) void k_kv(const unsigned short* __restrict__ krT,
                                            const unsigned short* __restrict__ fnchw,
                                            float* __restrict__ kvpart) {
  __shared__ __align__(16) short As[8192];   // 128 d-rows x 64 bf16 (swizzled)
  __shared__ __align__(16) short Bs[8192];   // 128 e-rows x 64 bf16 (swizzled)
  int tid = threadIdx.x;
  int bid = blockIdx.x;            // bh(32) x chunk(8)
  int bh = bid >> 3, chunk = bid & 7;
  int b = bh >> 2, h = bh & 3;
  int n_base = chunk * 512;
  int lane = tid & 63, wid = tid >> 6;
  int wm = (wid >> 1) * 64, wn = (wid & 1) * 64;
  int l15 = lane & 15, l4 = lane >> 4;

  const unsigned short* Ab = krT + ((size_t)b * 512 + h * 128) * 4096;
  const unsigned short* Vb = fnchw + ((size_t)b * 512 + h * 128) * 4096;
  f32x4 acc[4][4];
  #pragma unroll
  for (int i = 0; i < 4; i++)
    #pragma unroll
    for (int j = 0; j < 4; j++) acc[i][j] = (f32x4)0.f;

  int srow[4], sperm[4];
  #pragma unroll
  for (int i = 0; i < 4; i++) {
    int s = i * 256 + tid;
    srow[i] = s >> 3;
    sperm[i] = (s & 7) ^ (srow[i] & 7);
  }

  for (int t = 0; t < 8; ++t) {
    int k0 = n_base + (t << 6);
    if (t) __syncthreads();
    #pragma unroll
    for (int i = 0; i < 4; i++) {
      int s = i * 256 + tid;
      gload_lds16(Ab + (size_t)srow[i] * 4096 + k0 + sperm[i] * 8,
                  (char*)As + s * 16);
      gload_lds16(Vb + (size_t)srow[i] * 4096 + k0 + sperm[i] * 8,
                  (char*)Bs + s * 16);
    }
    __syncthreads();
    #pragma unroll
    for (int ks = 0; ks < 2; ++ks) {
      bf8 af[4], bfr[4];
      #pragma unroll
      for (int mt = 0; mt < 4; mt++) {
        int row = wm + mt * 16 + l15;
        int g = ks * 4 + l4;
        af[mt] = *(const bf8*)((const char*)As + row * 128 + ((g ^ (row & 7)) << 4));
      }
      #pragma unroll
      for (int nt = 0; nt < 4; nt++) {
        int row = wn + nt * 16 + l15;
        int g = ks * 4 + l4;
        bfr[nt] = *(const bf8*)((const char*)Bs + row * 128 + ((g ^ (row & 7)) << 4));
      }
      #pragma unroll
      for (int mt = 0; mt < 4; mt++)
        #pragma unroll
        for (int nt = 0; nt < 4; nt++)
          acc[mt][nt] = __builtin_amdgcn_mfma_f32_16x16x32_bf16(
              af[mt], bfr[nt], acc[mt][nt], 0, 0, 0);
    }
  }

  float* dst = kvpart + (size_t)(bh * 8 + chunk) * 16384;
  #pragma unroll
  for (int mt = 0; mt < 4; mt++) {
    #pragma unroll
    for (int nt = 0; nt < 4; nt++) {
      #pragma unroll
      for (int r = 0; r < 4; r++) {
        int d = wm + mt * 16 + l4 * 4 + r;
        int e = wn + nt * 16 + l15;
        dst[d * 128 + e] = acc[mt][nt][r];
      }
    }
  }
}

// ---------------- kv finalize: sum 8 partials, write bf16 kvT [e][d] --------
__global__ __launch_bounds__(256) void k_kv_fin(const float* __restrict__ part,
                                                unsigned short* __restrict__ kvT) {
  int bh = blockIdx.x;             // 32
  int tid = threadIdx.x;
  for (int idx = tid; idx < 16384; idx += 256) {
    int e = idx >> 7, d = idx & 127;
    float s = 0;
    for (int ch = 0; ch < 8; ch++)
      s += part[(size_t)(bh * 8 + ch) * 16384 + d * 128 + e];
    kvT[(size_t)bh * 16384 + idx] = f2bf(s * (1.0f / 4096.0f));
  }
}

// ---------------- lepe: 3x3 depthwise on bf16 fused --> writes d_out --------
__global__ __launch_bounds__(256) void k_lepe(const unsigned short* __restrict__ fnchw,
                                              const float* __restrict__ lw,
                                              const float* __restrict__ lb,
                                              float* __restrict__ out) {
  __shared__ float sm[66][67];
  __shared__ float wl[9];
  int tid = threadIdx.x;
  int bc = blockIdx.x;
  int c = bc & 511;
  const unsigned short* fp = fnchw + (size_t)bc * 4096;
  for (int idx = tid; idx < 4356; idx += 256) {
    int pr = idx / 66, pc = idx - pr * 66;
    int gr = pr - 1, gc = pc - 1;
    float v = 0.f;
    if ((unsigned)gr < 64u && (unsigned)gc < 64u) v = bf2f(fp[gr * 64 + gc]);
    sm[pr][pc] = v;
  }
  if (tid < 9) wl[tid] = lw[c * 9 + tid];
  __syncthreads();
  int r = tid >> 2, cb = (tid & 3) << 4;
  float bias = lb[c];
  float accv[16];
  #pragma unroll
  for (int i = 0; i < 16; i++) accv[i] = bias;
  #pragma unroll
  for (int dy = 0; dy < 3; dy++) {
    const float* row = &sm[r + dy][cb];
    float v[18];
    #pragma unroll
    for (int o = 0; o < 18; ++o) v[o] = row[o];
    #pragma unroll
    for (int dx = 0; dx < 3; dx++) {
      float wv = wl[dy * 3 + dx];
      #pragma unroll
      for (int i = 0; i < 16; i++) accv[i] = fmaf(wv, v[i + dx], accv[i]);
    }
  }
  float* op = out + (size_t)bc * 4096 + r * 64 + cb;
  #pragma unroll
  for (int i = 0; i < 16; i += 4)
    *(float4*)&op[i] = make_float4(accv[i], accv[i + 1], accv[i + 2], accv[i + 3]);
}

// ---------------- attention (k_qk-clone GEMM): out += z * (q_rope @ kvT^T) --
__global__ __launch_bounds__(256) void k_attn(const unsigned short* __restrict__ qr,
                                              const unsigned short* __restrict__ kvT,
                                              const float* __restrict__ zbuf,
                                              float* __restrict__ out) {
  __shared__ __align__(16) short As[8192];   // 128 token-rows x 64 bf16
  __shared__ __align__(16) short Bs[8192];   // 128 e-rows x 64 bf16
  __shared__ float zl[128];
  int tid = threadIdx.x;
  int bid = blockIdx.x;
  int sw = (bid & 7) * 128 + (bid >> 3);   // 1024 % 8 == 0 bijective XCD swizzle
  int b = sw >> 7, rem = sw & 127;
  int h = rem >> 5, mt_blk = rem & 31;
  int bh = b * 4 + h;
  int m0 = mt_blk << 7;
  int lane = tid & 63, wid = tid >> 6;
  int wm = (wid >> 1) * 64, wn = (wid & 1) * 64;
  int l15 = lane & 15, l4 = lane >> 4;

  const unsigned short* Ab = qr + (size_t)b * 4096 * 512 + h * 128;
  const unsigned short* Bb = kvT + (size_t)bh * 16384;
  if (tid < 128) zl[tid] = zbuf[(size_t)bh * 4096 + m0 + tid];

  f32x4 acc[4][4];
  #pragma unroll
  for (int i = 0; i < 4; i++)
    #pragma unroll
    for (int j = 0; j < 4; j++) acc[i][j] = (f32x4)0.f;

  int srow[4], sperm[4];
  #pragma unroll
  for (int i = 0; i < 4; i++) {
    int s = i * 256 + tid;
    srow[i] = s >> 3;
    sperm[i] = (s & 7) ^ (srow[i] & 7);
  }

  for (int t = 0; t < 2; ++t) {
    int c0 = t << 6;
    if (t) __syncthreads();
    #pragma unroll
    for (int i = 0; i < 4; i++) {
      int s = i * 256 + tid;
      gload_lds16(Ab + (size_t)(m0 + srow[i]) * 512 + c0 + sperm[i] * 8,
                  (char*)As + s * 16);
      gload_lds16(Bb + srow[i] * 128 + c0 + sperm[i] * 8,
                  (char*)Bs + s * 16);
    }
    __syncthreads();
    #pragma unroll
    for (int ks = 0; ks < 2; ++ks) {
      bf8 af[4], bfr[4];
      #pragma unroll
      for (int mt = 0; mt < 4; mt++) {
        int row = wm + mt * 16 + l15;
        int g = ks * 4 + l4;
        af[mt] = *(const bf8*)((const char*)As + row * 128 + ((g ^ (row & 7)) << 4));
      }
      #pragma unroll
      for (int nt = 0; nt < 4; nt++) {
        int row = wn + nt * 16 + l15;
        int g = ks * 4 + l4;
        bfr[nt] = *(const bf8*)((const char*)Bs + row * 128 + ((g ^ (row & 7)) << 4));
      }
      #pragma unroll
      for (int mt = 0; mt < 4; mt++)
        #pragma unroll
        for (int nt = 0; nt < 4; nt++)
          acc[mt][nt] = __builtin_amdgcn_mfma_f32_16x16x32_bf16(
              af[mt], bfr[nt], acc[mt][nt], 0, 0, 0);
    }
  }

  #pragma unroll
  for (int mt = 0; mt < 4; mt++) {
    int tl = wm + mt * 16 + l4 * 4;        // local token base (aligned 4)
    float4 zv = make_float4(zl[tl], zl[tl + 1], zl[tl + 2], zl[tl + 3]);
    #pragma unroll
    for (int nt = 0; nt < 4; nt++) {
      int e = wn + nt * 16 + l15;
      float* op = &out[((size_t)b * 512 + h * 128 + e) * 4096 + m0 + tl];
      float4 o4 = *(float4*)op;
      o4.x += acc[mt][nt][0] * zv.x;
      o4.y += acc[mt][nt][1] * zv.y;
      o4.z += acc[mt][nt][2] * zv.z;
      o4.w += acc[mt][nt][3] * zv.w;
      *(float4*)op = o4;
    }
  }
}

// ---------------------------------------------------------------------------
extern "C" void kernel_launch(void* const* d_in, const int* in_sizes, int n_in,
                              void* d_out, int out_size, void* d_ws, size_t ws_size,
                              hipStream_t stream) {
  (void)in_sizes; (void)n_in; (void)out_size; (void)ws_size;
  const float* x   = (const float*)d_in[0];
  const float* cw0 = (const float*)d_in[1];
  const float* cb0 = (const float*)d_in[2];
  const float* gw0 = (const float*)d_in[3];
  const float* gb0 = (const float*)d_in[4];
  const float* cw1 = (const float*)d_in[5];
  const float* cb1 = (const float*)d_in[6];
  const float* gw1 = (const float*)d_in[7];
  const float* gb1 = (const float*)d_in[8];
  const float* cw2 = (const float*)d_in[9];
  const float* cb2 = (const float*)d_in[10];
  const float* gw2 = (const float*)d_in[11];
  const float* gb2 = (const float*)d_in[12];
  const float* cw3 = (const float*)d_in[13];
  const float* cb3 = (const float*)d_in[14];
  const float* gw3 = (const float*)d_in[15];
  const float* gb3 = (const float*)d_in[16];
  const float* qkw = (const float*)d_in[17];
  const float* lw  = (const float*)d_in[18];
  const float* lb  = (const float*)d_in[19];
  float* out = (float*)d_out;
  float* ws  = (float*)d_ws;

  float* fslot    = ws;                         // 16,777,216 f (bf16 fnchw + qropebf)
  float* qslot    = fslot + 16777216;           // 16,777,216 f (lvl0 -> bf16 q)
  float* convpart = qslot + 16777216;           // 32,768 f
  float* gnstats  = convpart + 32768;           // 256 f
  float* tab      = gnstats + 256;              // 32,768 f
  float* kmp      = tab + 32768;                // 262,144 f
  float* kmean    = kmp + 262144;               // 4,096 f
  float* zbuf     = kmean + 4096;               // 131,072 f
  float* wslot    = zbuf + 131072;              // 262,144 f (wbf -> kvT)
  float* regionR  = wslot + 262144;             // 8,388,608 f (fbf -> krT)
  float* kvpart   = regionR + 8388608;          // 4,194,304 f
  // aliases (lifetimes disjoint, stream-ordered):
  unsigned short* lvl0    = (unsigned short*)qslot;   // dead after k_fused_tp
  unsigned short* lvl1    = (unsigned short*)kvpart;  // dead after k_fused_tp
  unsigned short* lvl2    = (unsigned short*)out;     // dead after k_fused_tp
  unsigned short* lvl3    = (unsigned short*)out + 16777216;
  unsigned short* fnchw   = (unsigned short*)fslot;            // bf16 NCHW fused
  unsigned short* qropebf = (unsigned short*)fslot + 16777216; // upper half of slot
  unsigned short* qbf     = (unsigned short*)qslot;   // bf16 q (after lvl0 dead)
  unsigned short* kbf     = (unsigned short*)out;     // bf16 k (dead after krT)
  unsigned short* fbf     = (unsigned short*)regionR; // written by k_fused_tp
  unsigned short* krT     = (unsigned short*)regionR; // written by k_krT (after k_qk)
  unsigned short* wbf     = (unsigned short*)wslot;   // dead after k_qk
  unsigned short* kvT     = (unsigned short*)wslot;   // written by k_kv_fin

  k_ropetab<<<dim3(64), dim3(256), 0, stream>>>(tab);
  k_conv4<<<dim3(4096), dim3(256), 0, stream>>>(
      x, cw0, cb0, cw1, cb1, cw2, cb2, cw3, cb3, convpart,
      lvl0, lvl1, lvl2, lvl3);
  k_gn_stats<<<dim3(128), dim3(128), 0, stream>>>(convpart, gnstats);
  k_fused_tp<<<dim3(4096), dim3(256), 0, stream>>>(
      lvl0, lvl1, lvl2, lvl3,
      gw0, gb0, gw1, gb1, gw2, gb2, gw3, gb3, gnstats, fnchw, fbf);
  k_wcvt<<<dim3(512), dim3(256), 0, stream>>>(qkw, wbf);
  k_qk<<<dim3(2048), dim3(256), 0, stream>>>(fbf, wbf, qbf, kbf);
  k_krT<<<dim3(4096), dim3(256), 0, stream>>>(kbf, tab, krT, kmp);
  k_kmean_fin<<<dim3(8), dim3(512), 0, stream>>>(kmp, kmean);
  k_kv<<<dim3(256), dim3(256), 0, stream>>>(krT, fnchw, kvpart);
  k_kv_fin<<<dim3(32), dim3(256), 0, stream>>>(kvpart, kvT);
  k_lepe<<<dim3(4096), dim3(256), 0, stream>>>(fnchw, lw, lb, out);
  k_zrope<<<dim3(8192), dim3(256), 0, stream>>>(qbf, kmean, tab, zbuf, qropebf);
  k_attn<<<dim3(1024), dim3(256), 0, stream>>>(qropebf, kvT, zbuf, out);
}

// Round 18
// 470.295 us; speedup vs baseline: 1.3172x; 1.3172x over previous
//
#include <hip/hip_runtime.h>
#include <math.h>

// ---------------------------------------------------------------------------
// Problem constants: B=8, C=512, H=W=64, N=4096, groups=4 (128 ch/group),
// heads=4 (hd=128), k_max=256 rope pairs, rope angle = wpos * theta[kidx].
// ---------------------------------------------------------------------------

typedef __attribute__((ext_vector_type(8))) short bf8;     // 8 bf16 (4 VGPR)
typedef __attribute__((ext_vector_type(4))) float f32x4;   // MFMA acc

__device__ __forceinline__ float waveSum(float v) {
  #pragma unroll
  for (int o = 32; o; o >>= 1) v += __shfl_down(v, o, 64);
  return v;
}

__device__ __forceinline__ unsigned short f2bf(float f) {
  unsigned u = __float_as_uint(f);
  unsigned r = u + 0x7fffu + ((u >> 16) & 1u);
  return (unsigned short)(r >> 16);
}

__device__ __forceinline__ float bf2f(unsigned short u) {
  return __uint_as_float((unsigned)u << 16);
}

__device__ __forceinline__ void gload_lds16(const void* g, void* l) {
  __builtin_amdgcn_global_load_lds(
      (const __attribute__((address_space(1))) unsigned*)g,
      (__attribute__((address_space(3))) unsigned*)l, 16, 0, 0);
}

// ---------------- rope cos/sin table: tab[wpos*256 + kidx] = {cos,sin} ------
__global__ __launch_bounds__(256) void k_ropetab(float* __restrict__ tab) {
  int idx = blockIdx.x * 256 + threadIdx.x;   // 16384 = 64 wpos * 256 kidx
  int w = idx >> 8, kk = idx & 255;
  float theta = powf(10000.0f, -(float)kk * (1.0f / 256.0f));
  float ang = (float)w * theta;
  tab[2 * idx]     = cosf(ang);
  tab[2 * idx + 1] = sinf(ang);
}

// ---------------- depthwise conv helper: 8 pixels/thread (3x proven) --------
// sm padded to [72][73]; 512-thread map r=tid>>3, cb=(tid&7)*8:
// bank = (9r' + 8q) mod 32 over a wave -> exactly 2 lanes/bank (free, m136).
// NOTE: per-level acc[8] + <=8-wide stores is the ONLY structure that avoids
// spills/occupancy cliffs (rounds 6/9/11/15/17 all failed otherwise).
template <int K>
__device__ __forceinline__ void conv8(float (*sm)[73], const float* wl,
                                      int r, int cb, float bias, float acc[8]) {
  constexpr int P = (K - 1) / 2;
  #pragma unroll
  for (int i = 0; i < 8; i++) acc[i] = bias;
  #pragma unroll
  for (int dy = 0; dy < K; ++dy) {
    const float* row = &sm[r + dy - P + 4][cb - P + 4];
    float v[8 + K - 1];
    #pragma unroll
    for (int o = 0; o < 8 + K - 1; ++o) v[o] = row[o];
    #pragma unroll
    for (int dx = 0; dx < K; ++dx) {
      float wv = wl[dy * K + dx];
      #pragma unroll
      for (int i = 0; i < 8; i++) acc[i] = fmaf(wv, v[i + dx], acc[i]);
    }
  }
}

__device__ __forceinline__ void load_plane512(const float* __restrict__ xp,
                                              float (*sm)[73], int tid) {
  for (int idx = tid; idx < 5184; idx += 512) {
    int pr = idx / 72, pc = idx - pr * 72;
    int gr = pr - 4, gc = pc - 4;
    float v = 0.f;
    if ((unsigned)gr < 64u && (unsigned)gc < 64u) v = xp[gr * 64 + gc];
    sm[pr][pc] = v;
  }
}

__device__ __forceinline__ void load_weights512(const float* w0, const float* w1,
                                                const float* w2, const float* w3,
                                                float* wl, int c, int tid) {
  if (tid < 9)               wl[tid] = w0[c * 9  + tid];
  else if (tid < 34)         wl[tid] = w1[c * 25 + tid - 9];
  else if (tid < 83)         wl[tid] = w2[c * 49 + tid - 34];
  else if (tid < 164)        wl[tid] = w3[c * 81 + tid - 83];
}

__device__ __forceinline__ void reduce_write2_512(float s, float sq, float* red,
                                                  int tid, float* dst) {
  s = waveSum(s); sq = waveSum(sq);
  int wid = tid >> 6, lane = tid & 63;
  if (lane == 0) { red[wid] = s; red[8 + wid] = sq; }
  __syncthreads();
  if (tid == 0) {
    float S = 0.f, SQ = 0.f;
    #pragma unroll
    for (int i = 0; i < 8; i++) { S += red[i]; SQ += red[8 + i]; }
    dst[0] = S; dst[1] = SQ;
  }
  __syncthreads();
}

// ---------------- single-staging conv (round-12/14/16 proven: VGPR 56) ------
__global__ __launch_bounds__(512) void k_conv4(
    const float* __restrict__ x,
    const float* __restrict__ w0, const float* __restrict__ b0,
    const float* __restrict__ w1, const float* __restrict__ b1,
    const float* __restrict__ w2, const float* __restrict__ b2,
    const float* __restrict__ w3, const float* __restrict__ b3,
    float* __restrict__ part,
    unsigned short* __restrict__ l0, unsigned short* __restrict__ l1,
    unsigned short* __restrict__ l2, unsigned short* __restrict__ l3) {
  __shared__ float sm[72][73];
  __shared__ float wl[164];
  __shared__ float red[16];
  int tid = threadIdx.x;
  int bc = blockIdx.x;             // b*512 + c
  int b = bc >> 9, c = bc & 511;
  load_plane512(x + (size_t)bc * 4096, sm, tid);
  load_weights512(w0, w1, w2, w3, wl, c, tid);
  __syncthreads();
  int r = tid >> 3, cb = (tid & 7) << 3;
  size_t obase = (size_t)bc * 4096 + r * 64 + cb;
  float acc[8];
  float s, sq;
  unsigned short o[8];

  // ---- level 0 (K=3) ----
  conv8<3>(sm, &wl[0], r, cb, b0[c], acc);
  s = 0; sq = 0;
  #pragma unroll
  for (int i = 0; i < 8; i++) {
    s += acc[i]; sq = fmaf(acc[i], acc[i], sq); o[i] = f2bf(acc[i]);
  }
  *(uint4*)&l0[obase] = *(uint4*)&o[0];
  reduce_write2_512(s, sq, red, tid, part + ((size_t)(0 * 8 + b) * 512 + c) * 2);
  __builtin_amdgcn_sched_barrier(0);

  // ---- level 1 (K=5) ----
  conv8<5>(sm, &wl[9], r, cb, b1[c], acc);
  s = 0; sq = 0;
  #pragma unroll
  for (int i = 0; i < 8; i++) {
    s += acc[i]; sq = fmaf(acc[i], acc[i], sq); o[i] = f2bf(acc[i]);
  }
  *(uint4*)&l1[obase] = *(uint4*)&o[0];
  reduce_write2_512(s, sq, red, tid, part + ((size_t)(1 * 8 + b) * 512 + c) * 2);
  __builtin_amdgcn_sched_barrier(0);

  // ---- level 2 (K=7) ----
  conv8<7>(sm, &wl[34], r, cb, b2[c], acc);
  s = 0; sq = 0;
  #pragma unroll
  for (int i = 0; i < 8; i++) {
    s += acc[i]; sq = fmaf(acc[i], acc[i], sq); o[i] = f2bf(acc[i]);
  }
  *(uint4*)&l2[obase] = *(uint4*)&o[0];
  reduce_write2_512(s, sq, red, tid, part + ((size_t)(2 * 8 + b) * 512 + c) * 2);
  __builtin_amdgcn_sched_barrier(0);

  // ---- level 3 (K=9) ----
  conv8<9>(sm, &wl[83], r, cb, b3[c], acc);
  s = 0; sq = 0;
  #pragma unroll
  for (int i = 0; i < 8; i++) {
    s += acc[i]; sq = fmaf(acc[i], acc[i], sq); o[i] = f2bf(acc[i]);
  }
  *(uint4*)&l3[obase] = *(uint4*)&o[0];
  reduce_write2_512(s, sq, red, tid, part + ((size_t)(3 * 8 + b) * 512 + c) * 2);
}

// ---------------- GN stats: mean/rstd per (level,b,group) -------------------
__global__ __launch_bounds__(128) void k_gn_stats(const float* __restrict__ part,
                                                  float* __restrict__ stats) {
  int blk = blockIdx.x;            // l*32 + b*4 + g, 128 blocks
  int tid = threadIdx.x;           // 128 = channels within group
  int g = blk & 3, bb = (blk >> 2) & 7, l = blk >> 5;
  const float* p = part + ((size_t)(l * 8 + bb) * 512 + g * 128 + tid) * 2;
  float s = p[0], sq = p[1];
  s = waveSum(s); sq = waveSum(sq);
  __shared__ float red[4];
  int wid = tid >> 6, lane = tid & 63;
  if (lane == 0) { red[wid] = s; red[2 + wid] = sq; }
  __syncthreads();
  if (tid == 0) {
    float S = red[0] + red[1], SQ = red[2] + red[3];
    const float inv = 1.0f / (128.0f * 4096.0f);
    float mean = S * inv;
    float var = SQ * inv - mean * mean;
    stats[blk * 2] = mean;
    stats[blk * 2 + 1] = rsqrtf(var + 1e-5f);
  }
}

// ---------------- fused GN+sigmoid+avg: write bf16 NCHW + bf16 token-major --
__global__ __launch_bounds__(256) void k_fused_tp(
    const unsigned short* __restrict__ l0, const unsigned short* __restrict__ l1,
    const unsigned short* __restrict__ l2, const unsigned short* __restrict__ l3,
    const float* __restrict__ gw0, const float* __restrict__ gb0,
    const float* __restrict__ gw1, const float* __restrict__ gb1,
    const float* __restrict__ gw2, const float* __restrict__ gb2,
    const float* __restrict__ gw3, const float* __restrict__ gb3,
    const float* __restrict__ stats, unsigned short* __restrict__ fnchw,
    unsigned short* __restrict__ fbf) {
  __shared__ float smT[64][65];
  int tid = threadIdx.x;
  int bid = blockIdx.x;            // b(8) x ct(8) x nt(64)
  int nt = bid & 63, ct = (bid >> 6) & 7, b = bid >> 9;
  int c0 = ct << 6, n0 = nt << 6;
  int c_loc = tid >> 2, nq = tid & 3;
  int c = c0 + c_loc, g = c >> 7;
  float m0 = stats[(0 * 32 + b * 4 + g) * 2], r0 = stats[(0 * 32 + b * 4 + g) * 2 + 1];
  float m1 = stats[(1 * 32 + b * 4 + g) * 2], r1 = stats[(1 * 32 + b * 4 + g) * 2 + 1];
  float m2 = stats[(2 * 32 + b * 4 + g) * 2], r2 = stats[(2 * 32 + b * 4 + g) * 2 + 1];
  float m3 = stats[(3 * 32 + b * 4 + g) * 2], r3 = stats[(3 * 32 + b * 4 + g) * 2 + 1];
  float a0 = r0 * gw0[c], c0p = gb0[c] - m0 * a0;
  float a1 = r1 * gw1[c], c1p = gb1[c] - m1 * a1;
  float a2 = r2 * gw2[c], c2p = gb2[c] - m2 * a2;
  float a3 = r3 * gw3[c], c3p = gb3[c] - m3 * a3;
  size_t base = ((size_t)b * 512 + c) * 4096 + n0 + nq * 16;
  uint4 u0a = *(const uint4*)&l0[base], u0b = *(const uint4*)&l0[base + 8];
  uint4 u1a = *(const uint4*)&l1[base], u1b = *(const uint4*)&l1[base + 8];
  uint4 u2a = *(const uint4*)&l2[base], u2b = *(const uint4*)&l2[base + 8];
  uint4 u3a = *(const uint4*)&l3[base], u3b = *(const uint4*)&l3[base + 8];
  float outv[16];
  #pragma unroll
  for (int i = 0; i < 8; i++) {
    float t0 = fmaf(bf2f(((const unsigned short*)&u0a)[i]), a0, c0p);
    float t1 = fmaf(bf2f(((const unsigned short*)&u1a)[i]), a1, c1p);
    float t2 = fmaf(bf2f(((const unsigned short*)&u2a)[i]), a2, c2p);
    float t3 = fmaf(bf2f(((const unsigned short*)&u3a)[i]), a3, c3p);
    float s = 1.0f / (1.0f + __expf(-t0)) + 1.0f / (1.0f + __expf(-t1)) +
              1.0f / (1.0f + __expf(-t2)) + 1.0f / (1.0f + __expf(-t3));
    outv[i] = s * 0.25f;
  }
  #pragma unroll
  for (int i = 0; i < 8; i++) {
    float t0 = fmaf(bf2f(((const unsigned short*)&u0b)[i]), a0, c0p);
    float t1 = fmaf(bf2f(((const unsigned short*)&u1b)[i]), a1, c1p);
    float t2 = fmaf(bf2f(((const unsigned short*)&u2b)[i]), a2, c2p);
    float t3 = fmaf(bf2f(((const unsigned short*)&u3b)[i]), a3, c3p);
    float s = 1.0f / (1.0f + __expf(-t0)) + 1.0f / (1.0f + __expf(-t1)) +
              1.0f / (1.0f + __expf(-t2)) + 1.0f / (1.0f + __expf(-t3));
    outv[8 + i] = s * 0.25f;
  }
  unsigned short ob[16];
  #pragma unroll
  for (int i = 0; i < 16; i++) ob[i] = f2bf(outv[i]);
  *(uint4*)&fnchw[base]     = *(uint4*)&ob[0];
  *(uint4*)&fnchw[base + 8] = *(uint4*)&ob[8];
  #pragma unroll
  for (int i = 0; i < 16; i++) smT[c_loc][nq * 16 + i] = outv[i];
  __syncthreads();
  int cc = tid & 63, r_s = tid >> 6;
  #pragma unroll
  for (int rr = 0; rr < 64; rr += 4)
    fbf[((size_t)b * 4096 + n0 + rr + r_s) * 512 + c0 + cc] = f2bf(smT[cc][rr + r_s]);
}

// ---------------- weight convert: qkw f32 [1024][512] -> bf16 ---------------
__global__ __launch_bounds__(256) void k_wcvt(const float* __restrict__ qkw,
                                              unsigned short* __restrict__ wbf) {
  int gid = blockIdx.x * 256 + threadIdx.x;   // 131072 threads x4 elems
  float4 v = *(const float4*)&qkw[(size_t)gid * 4];
  short4 o;
  o.x = (short)f2bf(v.x); o.y = (short)f2bf(v.y);
  o.z = (short)f2bf(v.z); o.w = (short)f2bf(v.w);
  *(short4*)&wbf[(size_t)gid * 4] = o;
}

// ---------------- qk GEMM (bf16 MFMA): bf16 q/k outputs ---------------------
__global__ __launch_bounds__(256) void k_qk(const unsigned short* __restrict__ fbf,
                                            const unsigned short* __restrict__ wbf,
                                            unsigned short* __restrict__ qbf,
                                            unsigned short* __restrict__ kbf) {
  __shared__ __align__(16) short As[8192];   // 128 rows x 64 bf16 (swizzled)
  __shared__ __align__(16) short Bs[8192];
  int tid = threadIdx.x;
  int bid = blockIdx.x;
  // bijective XCD swizzle (2048 % 8 == 0): XCD x works batch x entirely.
  int sw = (bid & 7) * 256 + (bid >> 3);
  int b = sw >> 8, rem = sw & 255;
  int mt_blk = rem >> 3, jt = rem & 7;
  int m0 = mt_blk << 7, j0 = jt << 7;
  int lane = tid & 63, wid = tid >> 6;
  int wm = (wid >> 1) * 64, wn = (wid & 1) * 64;
  int l15 = lane & 15, l4 = lane >> 4;

  const unsigned short* Ab = fbf + (size_t)b * 4096 * 512;
  f32x4 acc[4][4];
  #pragma unroll
  for (int i = 0; i < 4; i++)
    #pragma unroll
    for (int j = 0; j < 4; j++) acc[i][j] = (f32x4)0.f;

  int srow[4], sperm[4];
  #pragma unroll
  for (int i = 0; i < 4; i++) {
    int s = i * 256 + tid;
    srow[i] = s >> 3;
    sperm[i] = (s & 7) ^ (srow[i] & 7);
  }

  for (int t = 0; t < 8; ++t) {
    int c0 = t << 6;
    if (t) __syncthreads();
    #pragma unroll
    for (int i = 0; i < 4; i++) {
      int s = i * 256 + tid;
      gload_lds16(Ab + (size_t)(m0 + srow[i]) * 512 + c0 + sperm[i] * 8,
                  (char*)As + s * 16);
      gload_lds16(wbf + (size_t)(j0 + srow[i]) * 512 + c0 + sperm[i] * 8,
                  (char*)Bs + s * 16);
    }
    __syncthreads();
    #pragma unroll
    for (int ks = 0; ks < 2; ++ks) {
      bf8 af[4], bfr[4];
      #pragma unroll
      for (int mt = 0; mt < 4; mt++) {
        int row = wm + mt * 16 + l15;
        int g = ks * 4 + l4;
        af[mt] = *(const bf8*)((const char*)As + row * 128 + ((g ^ (row & 7)) << 4));
      }
      #pragma unroll
      for (int nt = 0; nt < 4; nt++) {
        int row = wn + nt * 16 + l15;
        int g = ks * 4 + l4;
        bfr[nt] = *(const bf8*)((const char*)Bs + row * 128 + ((g ^ (row & 7)) << 4));
      }
      #pragma unroll
      for (int mt = 0; mt < 4; mt++)
        #pragma unroll
        for (int nt = 0; nt < 4; nt++)
          acc[mt][nt] = __builtin_amdgcn_mfma_f32_16x16x32_bf16(
              af[mt], bfr[nt], acc[mt][nt], 0, 0, 0);
    }
  }

  unsigned short* dst; int jb;
  if (j0 < 512) { dst = qbf; jb = j0; } else { dst = kbf; jb = j0 - 512; }
  #pragma unroll
  for (int mt = 0; mt < 4; mt++) {
    #pragma unroll
    for (int nt = 0; nt < 4; nt++) {
      #pragma unroll
      for (int r = 0; r < 4; r++) {
        float v = acc[mt][nt][r];
        v = v > 0.f ? v + 1.f : __expf(v);   // elu(x)+1
        int token = m0 + wm + mt * 16 + l4 * 4 + r;
        int chan = jb + wn + nt * 16 + l15;
        dst[((size_t)b * 4096 + token) * 512 + chan] = f2bf(v);
      }
    }
  }
}

// ---------------- krT: transpose+rope kbf bf16 [n][c] -> krT bf16 [c][n] ----
__global__ __launch_bounds__(256) void k_krT(const unsigned short* __restrict__ kbf,
                                             const float* __restrict__ tab,
                                             unsigned short* __restrict__ krT,
                                             float* __restrict__ kmp) {
  __shared__ float sm[64][65];
  int tid = threadIdx.x;
  int bid = blockIdx.x;            // b(8) x ct(8) x nt(64)
  int nt = bid & 63, ct = (bid >> 6) & 7, b = bid >> 9;
  int c0 = ct << 6, n0 = nt << 6;
  int cc = tid & 63, n_s = tid >> 6;
  #pragma unroll
  for (int nn = 0; nn < 64; nn += 4)
    sm[cc][nn + n_s] =
        bf2f(kbf[((size_t)b * 4096 + n0 + nn + n_s) * 512 + c0 + cc]);
  __syncthreads();
  int rc = tid >> 2, nq = tid & 3;
  int c = c0 + rc;
  int pairidx = c >> 1;
  int odd = c & 1;
  int partner = odd ? rc - 1 : rc + 1;
  unsigned short o[16];
  float colsum = 0.f;
  #pragma unroll
  for (int i = 0; i < 16; i++) {
    int nloc = nq * 16 + i;                    // wpos = nloc (n0 % 64 == 0)
    float2 cs = *(const float2*)&tab[2 * (nloc * 256 + pairidx)];
    float a = sm[rc][nloc], p = sm[partner][nloc];
    float r = odd ? fmaf(cs.x, a, cs.y * p) : fmaf(cs.x, a, -cs.y * p);
    o[i] = f2bf(r);
    colsum += a;                               // un-roped for kmean
  }
  *(uint4*)&krT[((size_t)b * 512 + c) * 4096 + n0 + nq * 16]     = *(uint4*)&o[0];
  *(uint4*)&krT[((size_t)b * 512 + c) * 4096 + n0 + nq * 16 + 8] = *(uint4*)&o[8];
  colsum += __shfl_xor(colsum, 1, 64);
  colsum += __shfl_xor(colsum, 2, 64);
  if (nq == 0) kmp[((size_t)b * 64 + nt) * 512 + c] = colsum;
}

// ---------------- kmean finalize ---------------------------------------------
__global__ __launch_bounds__(512) void k_kmean_fin(const float* __restrict__ kmp,
                                                   float* __restrict__ kmean) {
  int b = blockIdx.x, c = threadIdx.x;
  float s = 0.f;
  for (int nt = 0; nt < 64; nt++) s += kmp[((size_t)b * 64 + nt) * 512 + c];
  kmean[b * 512 + c] = s * (1.0f / 4096.0f);
}

// ---------------- z + q_rope fused, COALESCED, bf16 q input -----------------
__global__ __launch_bounds__(256) void k_zrope(const unsigned short* __restrict__ qbf,
                                               const float* __restrict__ kmean,
                                               const float* __restrict__ tab,
                                               float* __restrict__ zbuf,
                                               unsigned short* __restrict__ qr) {
  __shared__ float kml[512];
  int tid = threadIdx.x;
  int blk = blockIdx.x;            // 8192 blocks x 4 tokens
  int b = blk >> 10;               // 1024 blocks per batch
  kml[tid] = kmean[b * 512 + tid];
  kml[tid + 256] = kmean[b * 512 + 256 + tid];
  __syncthreads();
  int tok = blk * 4 + (tid >> 6);  // global token index (b*4096 + n)
  int pg = tid & 63;
  int n = tok & 4095;
  int wpos = n & 63;
  uint4 qu = *(const uint4*)&qbf[(size_t)tok * 512 + pg * 8];
  const unsigned short* qs = (const unsigned short*)&qu;
  float4 a  = make_float4(bf2f(qs[0]), bf2f(qs[1]), bf2f(qs[2]), bf2f(qs[3]));
  float4 b4 = make_float4(bf2f(qs[4]), bf2f(qs[5]), bf2f(qs[6]), bf2f(qs[7]));
  const float* tp = tab + 2 * (wpos * 256 + pg * 4);
  float4 t0 = *(const float4*)&tp[0];   // pairs 4pg, 4pg+1
  float4 t1 = *(const float4*)&tp[4];   // pairs 4pg+2, 4pg+3
  unsigned short o[8];
  o[0] = f2bf(t0.x * a.x - t0.y * a.y);
  o[1] = f2bf(t0.x * a.y + t0.y * a.x);
  o[2] = f2bf(t0.z * a.z - t0.w * a.w);
  o[3] = f2bf(t0.z * a.w + t0.w * a.z);
  o[4] = f2bf(t1.x * b4.x - t1.y * b4.y);
  o[5] = f2bf(t1.x * b4.y + t1.y * b4.x);
  o[6] = f2bf(t1.z * b4.z - t1.w * b4.w);
  o[7] = f2bf(t1.z * b4.w + t1.w * b4.z);
  *(uint4*)&qr[(size_t)tok * 512 + pg * 8] = *(uint4*)o;
  // z partial: dot(q[pg*8..+7], kmean[pg*8..+7])
  const float* km = &kml[pg * 8];
  float4 ka = *(const float4*)&km[0];
  float4 kb = *(const float4*)&km[4];
  float dot = a.x * ka.x + a.y * ka.y + a.z * ka.z + a.w * ka.w +
              b4.x * kb.x + b4.y * kb.y + b4.z * kb.z + b4.w * kb.w;
  dot += __shfl_xor(dot, 1, 64);
  dot += __shfl_xor(dot, 2, 64);
  dot += __shfl_xor(dot, 4, 64);
  dot += __shfl_xor(dot, 8, 64);
  if ((pg & 15) == 0) {
    int h = pg >> 4;
    zbuf[(size_t)(b * 4 + h) * 4096 + n] = 1.0f / (dot + 1e-6f);
  }
}

// ---------------- kv GEMM: both operands via gload_lds16 (bf16 NCHW V) ------
__global__ __launch_bounds__(256) void k_kv(const unsigned short* __restrict__ krT,
                                            const unsigned short* __restrict__ fnchw,
                                            float* __restrict__ kvpart) {
  __shared__ __align__(16) short As[8192];   // 128 d-rows x 64 bf16 (swizzled)
  __shared__ __align__(16) short Bs[8192];   // 128 e-rows x 64 bf16 (swizzled)
  int tid = threadIdx.x;
  int bid = blockIdx.x;            // bh(32) x chunk(8)
  int bh = bid >> 3, chunk = bid & 7;
  int b = bh >> 2, h = bh & 3;
  int n_base = chunk * 512;
  int lane = tid & 63, wid = tid >> 6;
  int wm = (wid >> 1) * 64, wn = (wid & 1) * 64;
  int l15 = lane & 15, l4 = lane >> 4;

  const unsigned short* Ab = krT + ((size_t)b * 512 + h * 128) * 4096;
  const unsigned short* Vb = fnchw + ((size_t)b * 512 + h * 128) * 4096;
  f32x4 acc[4][4];
  #pragma unroll
  for (int i = 0; i < 4; i++)
    #pragma unroll
    for (int j = 0; j < 4; j++) acc[i][j] = (f32x4)0.f;

  int srow[4], sperm[4];
  #pragma unroll
  for (int i = 0; i < 4; i++) {
    int s = i * 256 + tid;
    srow[i] = s >> 3;
    sperm[i] = (s & 7) ^ (srow[i] & 7);
  }

  for (int t = 0; t < 8; ++t) {
    int k0 = n_base + (t << 6);
    if (t) __syncthreads();
    #pragma unroll
    for (int i = 0; i < 4; i++) {
      int s = i * 256 + tid;
      gload_lds16(Ab + (size_t)srow[i] * 4096 + k0 + sperm[i] * 8,
                  (char*)As + s * 16);
      gload_lds16(Vb + (size_t)srow[i] * 4096 + k0 + sperm[i] * 8,
                  (char*)Bs + s * 16);
    }
    __syncthreads();
    #pragma unroll
    for (int ks = 0; ks < 2; ++ks) {
      bf8 af[4], bfr[4];
      #pragma unroll
      for (int mt = 0; mt < 4; mt++) {
        int row = wm + mt * 16 + l15;
        int g = ks * 4 + l4;
        af[mt] = *(const bf8*)((const char*)As + row * 128 + ((g ^ (row & 7)) << 4));
      }
      #pragma unroll
      for (int nt = 0; nt < 4; nt++) {
        int row = wn + nt * 16 + l15;
        int g = ks * 4 + l4;
        bfr[nt] = *(const bf8*)((const char*)Bs + row * 128 + ((g ^ (row & 7)) << 4));
      }
      #pragma unroll
      for (int mt = 0; mt < 4; mt++)
        #pragma unroll
        for (int nt = 0; nt < 4; nt++)
          acc[mt][nt] = __builtin_amdgcn_mfma_f32_16x16x32_bf16(
              af[mt], bfr[nt], acc[mt][nt], 0, 0, 0);
    }
  }

  float* dst = kvpart + (size_t)(bh * 8 + chunk) * 16384;
  #pragma unroll
  for (int mt = 0; mt < 4; mt++) {
    #pragma unroll
    for (int nt = 0; nt < 4; nt++) {
      #pragma unroll
      for (int r = 0; r < 4; r++) {
        int d = wm + mt * 16 + l4 * 4 + r;
        int e = wn + nt * 16 + l15;
        dst[d * 128 + e] = acc[mt][nt][r];
      }
    }
  }
}

// ---------------- kv finalize: sum 8 partials, write bf16 kvT [e][d] --------
__global__ __launch_bounds__(256) void k_kv_fin(const float* __restrict__ part,
                                                unsigned short* __restrict__ kvT) {
  int bh = blockIdx.x;             // 32
  int tid = threadIdx.x;
  for (int idx = tid; idx < 16384; idx += 256) {
    int e = idx >> 7, d = idx & 127;
    float s = 0;
    for (int ch = 0; ch < 8; ch++)
      s += part[(size_t)(bh * 8 + ch) * 16384 + d * 128 + e];
    kvT[(size_t)bh * 16384 + idx] = f2bf(s * (1.0f / 4096.0f));
  }
}

// ---------------- lepe: 3x3 depthwise on bf16 fused --> writes d_out --------
__global__ __launch_bounds__(256) void k_lepe(const unsigned short* __restrict__ fnchw,
                                              const float* __restrict__ lw,
                                              const float* __restrict__ lb,
                                              float* __restrict__ out) {
  __shared__ float sm[66][67];
  __shared__ float wl[9];
  int tid = threadIdx.x;
  int bc = blockIdx.x;
  int c = bc & 511;
  const unsigned short* fp = fnchw + (size_t)bc * 4096;
  for (int idx = tid; idx < 4356; idx += 256) {
    int pr = idx / 66, pc = idx - pr * 66;
    int gr = pr - 1, gc = pc - 1;
    float v = 0.f;
    if ((unsigned)gr < 64u && (unsigned)gc < 64u) v = bf2f(fp[gr * 64 + gc]);
    sm[pr][pc] = v;
  }
  if (tid < 9) wl[tid] = lw[c * 9 + tid];
  __syncthreads();
  int r = tid >> 2, cb = (tid & 3) << 4;
  float bias = lb[c];
  float accv[16];
  #pragma unroll
  for (int i = 0; i < 16; i++) accv[i] = bias;
  #pragma unroll
  for (int dy = 0; dy < 3; dy++) {
    const float* row = &sm[r + dy][cb];
    float v[18];
    #pragma unroll
    for (int o = 0; o < 18; ++o) v[o] = row[o];
    #pragma unroll
    for (int dx = 0; dx < 3; dx++) {
      float wv = wl[dy * 3 + dx];
      #pragma unroll
      for (int i = 0; i < 16; i++) accv[i] = fmaf(wv, v[i + dx], accv[i]);
    }
  }
  float* op = out + (size_t)bc * 4096 + r * 64 + cb;
  #pragma unroll
  for (int i = 0; i < 16; i += 4)
    *(float4*)&op[i] = make_float4(accv[i], accv[i + 1], accv[i + 2], accv[i + 3]);
}

// ---------------- attention (k_qk-clone GEMM): out += z * (q_rope @ kvT^T) --
__global__ __launch_bounds__(256) void k_attn(const unsigned short* __restrict__ qr,
                                              const unsigned short* __restrict__ kvT,
                                              const float* __restrict__ zbuf,
                                              float* __restrict__ out) {
  __shared__ __align__(16) short As[8192];   // 128 token-rows x 64 bf16
  __shared__ __align__(16) short Bs[8192];   // 128 e-rows x 64 bf16
  __shared__ float zl[128];
  int tid = threadIdx.x;
  int bid = blockIdx.x;
  int sw = (bid & 7) * 128 + (bid >> 3);   // 1024 % 8 == 0 bijective XCD swizzle
  int b = sw >> 7, rem = sw & 127;
  int h = rem >> 5, mt_blk = rem & 31;
  int bh = b * 4 + h;
  int m0 = mt_blk << 7;
  int lane = tid & 63, wid = tid >> 6;
  int wm = (wid >> 1) * 64, wn = (wid & 1) * 64;
  int l15 = lane & 15, l4 = lane >> 4;

  const unsigned short* Ab = qr + (size_t)b * 4096 * 512 + h * 128;
  const unsigned short* Bb = kvT + (size_t)bh * 16384;
  if (tid < 128) zl[tid] = zbuf[(size_t)bh * 4096 + m0 + tid];

  f32x4 acc[4][4];
  #pragma unroll
  for (int i = 0; i < 4; i++)
    #pragma unroll
    for (int j = 0; j < 4; j++) acc[i][j] = (f32x4)0.f;

  int srow[4], sperm[4];
  #pragma unroll
  for (int i = 0; i < 4; i++) {
    int s = i * 256 + tid;
    srow[i] = s >> 3;
    sperm[i] = (s & 7) ^ (srow[i] & 7);
  }

  for (int t = 0; t < 2; ++t) {
    int c0 = t << 6;
    if (t) __syncthreads();
    #pragma unroll
    for (int i = 0; i < 4; i++) {
      int s = i * 256 + tid;
      gload_lds16(Ab + (size_t)(m0 + srow[i]) * 512 + c0 + sperm[i] * 8,
                  (char*)As + s * 16);
      gload_lds16(Bb + srow[i] * 128 + c0 + sperm[i] * 8,
                  (char*)Bs + s * 16);
    }
    __syncthreads();
    #pragma unroll
    for (int ks = 0; ks < 2; ++ks) {
      bf8 af[4], bfr[4];
      #pragma unroll
      for (int mt = 0; mt < 4; mt++) {
        int row = wm + mt * 16 + l15;
        int g = ks * 4 + l4;
        af[mt] = *(const bf8*)((const char*)As + row * 128 + ((g ^ (row & 7)) << 4));
      }
      #pragma unroll
      for (int nt = 0; nt < 4; nt++) {
        int row = wn + nt * 16 + l15;
        int g = ks * 4 + l4;
        bfr[nt] = *(const bf8*)((const char*)Bs + row * 128 + ((g ^ (row & 7)) << 4));
      }
      #pragma unroll
      for (int mt = 0; mt < 4; mt++)
        #pragma unroll
        for (int nt = 0; nt < 4; nt++)
          acc[mt][nt] = __builtin_amdgcn_mfma_f32_16x16x32_bf16(
              af[mt], bfr[nt], acc[mt][nt], 0, 0, 0);
    }
  }

  #pragma unroll
  for (int mt = 0; mt < 4; mt++) {
    int tl = wm + mt * 16 + l4 * 4;        // local token base (aligned 4)
    float4 zv = make_float4(zl[tl], zl[tl + 1], zl[tl + 2], zl[tl + 3]);
    #pragma unroll
    for (int nt = 0; nt < 4; nt++) {
      int e = wn + nt * 16 + l15;
      float* op = &out[((size_t)b * 512 + h * 128 + e) * 4096 + m0 + tl];
      float4 o4 = *(float4*)op;
      o4.x += acc[mt][nt][0] * zv.x;
      o4.y += acc[mt][nt][1] * zv.y;
      o4.z += acc[mt][nt][2] * zv.z;
      o4.w += acc[mt][nt][3] * zv.w;
      *(float4*)op = o4;
    }
  }
}

// ---------------------------------------------------------------------------
extern "C" void kernel_launch(void* const* d_in, const int* in_sizes, int n_in,
                              void* d_out, int out_size, void* d_ws, size_t ws_size,
                              hipStream_t stream) {
  (void)in_sizes; (void)n_in; (void)out_size; (void)ws_size;
  const float* x   = (const float*)d_in[0];
  const float* cw0 = (const float*)d_in[1];
  const float* cb0 = (const float*)d_in[2];
  const float* gw0 = (const float*)d_in[3];
  const float* gb0 = (const float*)d_in[4];
  const float* cw1 = (const float*)d_in[5];
  const float* cb1 = (const float*)d_in[6];
  const float* gw1 = (const float*)d_in[7];
  const float* gb1 = (const float*)d_in[8];
  const float* cw2 = (const float*)d_in[9];
  const float* cb2 = (const float*)d_in[10];
  const float* gw2 = (const float*)d_in[11];
  const float* gb2 = (const float*)d_in[12];
  const float* cw3 = (const float*)d_in[13];
  const float* cb3 = (const float*)d_in[14];
  const float* gw3 = (const float*)d_in[15];
  const float* gb3 = (const float*)d_in[16];
  const float* qkw = (const float*)d_in[17];
  const float* lw  = (const float*)d_in[18];
  const float* lb  = (const float*)d_in[19];
  float* out = (float*)d_out;
  float* ws  = (float*)d_ws;

  float* fslot    = ws;                         // 16,777,216 f (bf16 fnchw + qropebf)
  float* qslot    = fslot + 16777216;           // 16,777,216 f (lvl0 -> bf16 q)
  float* convpart = qslot + 16777216;           // 32,768 f
  float* gnstats  = convpart + 32768;           // 256 f
  float* tab      = gnstats + 256;              // 32,768 f
  float* kmp      = tab + 32768;                // 262,144 f
  float* kmean    = kmp + 262144;               // 4,096 f
  float* zbuf     = kmean + 4096;               // 131,072 f
  float* wslot    = zbuf + 131072;              // 262,144 f (wbf -> kvT)
  float* regionR  = wslot + 262144;             // 8,388,608 f (fbf -> krT)
  float* kvpart   = regionR + 8388608;          // 4,194,304 f
  // aliases (lifetimes disjoint, stream-ordered):
  unsigned short* lvl0    = (unsigned short*)qslot;   // dead after k_fused_tp
  unsigned short* lvl1    = (unsigned short*)kvpart;  // dead after k_fused_tp
  unsigned short* lvl2    = (unsigned short*)out;     // dead after k_fused_tp
  unsigned short* lvl3    = (unsigned short*)out + 16777216;
  unsigned short* fnchw   = (unsigned short*)fslot;            // bf16 NCHW fused
  unsigned short* qropebf = (unsigned short*)fslot + 16777216; // upper half of slot
  unsigned short* qbf     = (unsigned short*)qslot;   // bf16 q (after lvl0 dead)
  unsigned short* kbf     = (unsigned short*)out;     // bf16 k (dead after krT)
  unsigned short* fbf     = (unsigned short*)regionR; // written by k_fused_tp
  unsigned short* krT     = (unsigned short*)regionR; // written by k_krT (after k_qk)
  unsigned short* wbf     = (unsigned short*)wslot;   // dead after k_qk
  unsigned short* kvT     = (unsigned short*)wslot;   // written by k_kv_fin

  k_ropetab<<<dim3(64), dim3(256), 0, stream>>>(tab);
  k_conv4<<<dim3(4096), dim3(512), 0, stream>>>(
      x, cw0, cb0, cw1, cb1, cw2, cb2, cw3, cb3, convpart,
      lvl0, lvl1, lvl2, lvl3);
  k_gn_stats<<<dim3(128), dim3(128), 0, stream>>>(convpart, gnstats);
  k_fused_tp<<<dim3(4096), dim3(256), 0, stream>>>(
      lvl0, lvl1, lvl2, lvl3,
      gw0, gb0, gw1, gb1, gw2, gb2, gw3, gb3, gnstats, fnchw, fbf);
  k_wcvt<<<dim3(512), dim3(256), 0, stream>>>(qkw, wbf);
  k_qk<<<dim3(2048), dim3(256), 0, stream>>>(fbf, wbf, qbf, kbf);
  k_krT<<<dim3(4096), dim3(256), 0, stream>>>(kbf, tab, krT, kmp);
  k_kmean_fin<<<dim3(8), dim3(512), 0, stream>>>(kmp, kmean);
  k_kv<<<dim3(256), dim3(256), 0, stream>>>(krT, fnchw, kvpart);
  k_kv_fin<<<dim3(32), dim3(256), 0, stream>>>(kvpart, kvT);
  k_lepe<<<dim3(4096), dim3(256), 0, stream>>>(fnchw, lw, lb, out);
  k_zrope<<<dim3(8192), dim3(256), 0, stream>>>(qbf, kmean, tab, zbuf, qropebf);
  k_attn<<<dim3(1024), dim3(256), 0, stream>>>(qropebf, kvT, zbuf, out);
}